// Round 1
// baseline (363.807 us; speedup 1.0000x reference)
//
#include <hip/hip_runtime.h>

#define NUM_HEADS 16
#define HEAD_DIM  64
#define HIDDEN    1024
#define SEQ       512
#define BATCH     8
#define NBH       128      // BATCH*NUM_HEADS
#define POSN      512      // 2*BUCKET
#define SCALE_F   0.07216878364870323f   // 1/sqrt(3*HEAD_DIM)

typedef __attribute__((ext_vector_type(8))) short  short8;
typedef __attribute__((ext_vector_type(4))) short  short4_t;
typedef __attribute__((ext_vector_type(4))) float  floatx4;

__device__ __forceinline__ float bits2f(short s) {
    union { unsigned u; float f; } x;
    x.u = ((unsigned)(unsigned short)s) << 16;
    return x.f;
}
__device__ __forceinline__ short f2bits(float f) {
    union { float f; unsigned u; } x;
    x.f = f;
    unsigned r = x.u + 0x7fffu + ((x.u >> 16) & 1u);
    return (short)(r >> 16);
}

// ---------------------------------------------------------------------------
// prep: fp32 -> bf16 conversion for inputs and rel_embeddings
// ---------------------------------------------------------------------------
__global__ void conv_pair(const float* __restrict__ a, const float* __restrict__ b,
                          short* __restrict__ oa, short* __restrict__ ob)
{
    const int idx = blockIdx.x * 256 + threadIdx.x;    // one float4 each
    floatx4 va = ((const floatx4*)a)[idx];
    floatx4 vb = ((const floatx4*)b)[idx];
    short4_t ra, rb;
#pragma unroll
    for (int i = 0; i < 4; i++) { ra[i] = f2bits(va[i]); rb[i] = f2bits(vb[i]); }
    ((short4_t*)oa)[idx] = ra;
    ((short4_t*)ob)[idx] = rb;
}

// ---------------------------------------------------------------------------
// prep: transpose + convert the 4 weight matrices [1024][1024] -> bf16 [n][c]
// ---------------------------------------------------------------------------
__global__ void wtrans(const float* __restrict__ w0, const float* __restrict__ w1,
                       const float* __restrict__ w2, const float* __restrict__ w3,
                       short* __restrict__ o0, short* __restrict__ o1,
                       short* __restrict__ o2, short* __restrict__ o3)
{
    __shared__ float tile[64][65];
    const int z = blockIdx.z;
    const float* src = (z == 0) ? w0 : (z == 1) ? w1 : (z == 2) ? w2 : w3;
    short*       dst = (z == 0) ? o0 : (z == 1) ? o1 : (z == 2) ? o2 : o3;
    const int c0 = blockIdx.x * 64, n0 = blockIdx.y * 64;
    const int t = threadIdx.x;
#pragma unroll
    for (int j = 0; j < 16; j++) {
        const int e = t + j * 256;
        tile[e >> 6][e & 63] = src[(long)(c0 + (e >> 6)) * 1024 + n0 + (e & 63)];
    }
    __syncthreads();
#pragma unroll
    for (int j = 0; j < 16; j++) {
        const int e = t + j * 256;
        dst[(long)(n0 + (e >> 6)) * 1024 + c0 + (e & 63)] = f2bits(tile[e & 63][e >> 6]);
    }
}

// ---------------------------------------------------------------------------
// prep: 1-D log-bucket table  ftab[delta+511] = clip(bucket(delta)+256, 0, 511)
// (mirrors reference fp32 op order; bucket(-d) = -bucket(d) makes one table
//  serve both c2p and p2c)
// ---------------------------------------------------------------------------
__global__ void ftab_build(int* __restrict__ ftab)
{
    const int i = blockIdx.x * 256 + threadIdx.x;
    if (i >= 1023) return;
    const int delta = i - 511;
    const float Cf = (float)log(511.0 / 128.0);   // math.log((MAX_POS-1)/mid) as f32
    float absp = (delta < 128 && delta > -128) ? 127.0f : fabsf((float)delta);
    float bucket;
    if (absp <= 128.0f) {
        bucket = (float)delta;
    } else {
        float lp = ceilf((logf(absp * (1.0f / 128.0f)) * 127.0f) / Cf) + 128.0f;
        bucket = (delta > 0) ? lp : -lp;
    }
    int bi = (int)bucket + 256;
    bi = min(max(bi, 0), 511);
    ftab[i] = bi;
}

// ---------------------------------------------------------------------------
// Generic NT GEMM: C[m,n] = sum_k A[m,k] * BT[n,k]   (bf16 in, fp32 acc)
// tile 128x128, BK=64, 256 threads (4 waves, 2x2), 16x16x32 bf16 MFMA
// MODE 0: proj  -> bf16 out laid out [b,h,s,d], + bias[n]
// MODE 1: plain -> bf16 out row-major [m*ldo+n], batched by z
// MODE 2: final -> fp32 out row-major + bias[n]
// ---------------------------------------------------------------------------
template<int MODE>
__global__ __launch_bounds__(256)
void gemm_nt(const short* __restrict__ A, long aBatch, int lda,
             const short* __restrict__ BT, long bBatch, int ldb,
             void* __restrict__ OutP, long oBatch, int ldo,
             const float* __restrict__ bias, int Kd)
{
    __shared__ __align__(16) short As[128 * 64];
    __shared__ __align__(16) short Bs[128 * 64];
    const int z = blockIdx.z;
    const short* Ab = A + (long)z * aBatch;
    const short* Bb = BT + (long)z * bBatch;
    const int m0 = blockIdx.x * 128, n0 = blockIdx.y * 128;
    const int t = threadIdx.x;
    const int l = t & 63, w = t >> 6;
    const int wm = w >> 1, wn = w & 1;
    const int lr = l & 15, lg = l >> 4;

    floatx4 acc[4][4];
#pragma unroll
    for (int i = 0; i < 4; i++)
#pragma unroll
        for (int j = 0; j < 4; j++) acc[i][j] = (floatx4){0.f, 0.f, 0.f, 0.f};

    for (int k0 = 0; k0 < Kd; k0 += 64) {
        __syncthreads();
#pragma unroll
        for (int j = 0; j < 4; j++) {
            const int chunk = t + j * 256;   // 1024 chunks of 16B per matrix
            const int row = chunk >> 3;      // 0..127
            const int cc  = chunk & 7;       // logical 16B chunk in row
            const int pc  = cc ^ (row & 7);  // XOR swizzle (bank-conflict-free reads)
            short8 va = *(const short8*)(Ab + (long)(m0 + row) * lda + k0 + cc * 8);
            *(short8*)((char*)As + row * 128 + pc * 16) = va;
            short8 vb = *(const short8*)(Bb + (long)(n0 + row) * ldb + k0 + cc * 8);
            *(short8*)((char*)Bs + row * 128 + pc * 16) = vb;
        }
        __syncthreads();
#pragma unroll
        for (int ks = 0; ks < 2; ks++) {
            short8 af[4], bfr[4];
#pragma unroll
            for (int i = 0; i < 4; i++) {
                const int mr = wm * 64 + i * 16 + lr;
                af[i] = *(const short8*)((char*)As + mr * 128 + (((ks * 4 + lg) ^ (mr & 7)) * 16));
                const int nr = wn * 64 + i * 16 + lr;
                bfr[i] = *(const short8*)((char*)Bs + nr * 128 + (((ks * 4 + lg) ^ (nr & 7)) * 16));
            }
#pragma unroll
            for (int i = 0; i < 4; i++)
#pragma unroll
                for (int j = 0; j < 4; j++)
                    acc[i][j] = __builtin_amdgcn_mfma_f32_16x16x32_bf16(af[i], bfr[j], acc[i][j], 0, 0, 0);
        }
    }

#pragma unroll
    for (int i = 0; i < 4; i++) {
#pragma unroll
        for (int j = 0; j < 4; j++) {
#pragma unroll
            for (int e = 0; e < 4; e++) {
                const int mg = m0 + wm * 64 + i * 16 + lg * 4 + e;
                const int ng = n0 + wn * 64 + j * 16 + lr;
                float v = acc[i][j][e];
                if (MODE == 0) {
                    v += bias[ng];
                    const int b = mg >> 9, s = mg & 511, h = ng >> 6, d = ng & 63;
                    ((short*)OutP)[((long)(b * NUM_HEADS + h) * SEQ + s) * HEAD_DIM + d] = f2bits(v);
                } else if (MODE == 1) {
                    ((short*)OutP)[(long)z * oBatch + (long)mg * ldo + ng] = f2bits(v);
                } else {
                    ((float*)OutP)[(long)mg * ldo + ng] = v + bias[ng];
                }
            }
        }
    }
}

// ---------------------------------------------------------------------------
// Fused attention per (b,h, 32-row q-tile):
//   QK^T (MFMA, operands straight from global/L2), + gathered c2p/p2c,
//   row softmax (shfl + LDS cross-wave), P->LDS (swizzled), PV (MFMA),
//   cross-wave reduce, normalize, write attn (bf16, [b*s][h*64+d]).
// 4 waves; wave w owns score columns [w*128, w*128+128).
// ---------------------------------------------------------------------------
__global__ __launch_bounds__(256)
void attn_fused(const short* __restrict__ Q, const short* __restrict__ K,
                const short* __restrict__ V,
                const short* __restrict__ c2pf, const short* __restrict__ p2cf,
                const int* __restrict__ ftab,
                short* __restrict__ attnO)
{
    __shared__ __align__(16) short Pl[32 * 512];   // swizzled P tile (unnormalized)
    __shared__ float red[2][4][32];
    __shared__ float rowS[32];
    __shared__ float attnred[32][64];
    __shared__ short ft[1024];

    const int qt = blockIdx.x, bh = blockIdx.y;
    const int q0 = qt * 32;
    const int t = threadIdx.x, l = t & 63, w = t >> 6;
    const int lr = l & 15, lg = l >> 4;
    const long pbase = (long)bh * SEQ * HEAD_DIM;
    const short* Qb = Q + pbase;
    const short* Kb = K + pbase;
    const short* Vb = V + pbase;
    const long sbase = (long)bh * SEQ * POSN;
    const short* c2pb = c2pf + sbase;
    const short* p2cb = p2cf + sbase;

    for (int i = t; i < 1024; i += 256) ft[i] = (short)((i < 1023) ? ftab[i] : 0);
    for (int i = t; i < 2048; i += 256) ((float*)attnred)[i] = 0.f;

    // Q fragments (held in regs for whole kernel)
    short8 aq[2][2];
#pragma unroll
    for (int mt = 0; mt < 2; mt++)
#pragma unroll
        for (int ks = 0; ks < 2; ks++)
            aq[mt][ks] = *(const short8*)(Qb + (q0 + mt * 16 + lr) * 64 + ks * 32 + lg * 8);

    floatx4 acc[2][8];
#pragma unroll
    for (int mt = 0; mt < 2; mt++)
#pragma unroll
        for (int nt = 0; nt < 8; nt++) acc[mt][nt] = (floatx4){0.f, 0.f, 0.f, 0.f};

    // QK^T
#pragma unroll
    for (int nt = 0; nt < 8; nt++) {
        const int kr = w * 128 + nt * 16 + lr;
        short8 kb0 = *(const short8*)(Kb + kr * 64 + lg * 8);
        short8 kb1 = *(const short8*)(Kb + kr * 64 + 32 + lg * 8);
#pragma unroll
        for (int mt = 0; mt < 2; mt++) {
            acc[mt][nt] = __builtin_amdgcn_mfma_f32_16x16x32_bf16(aq[mt][0], kb0, acc[mt][nt], 0, 0, 0);
            acc[mt][nt] = __builtin_amdgcn_mfma_f32_16x16x32_bf16(aq[mt][1], kb1, acc[mt][nt], 0, 0, 0);
        }
    }

    // gathered c2p/p2c adds + scale
#pragma unroll
    for (int mt = 0; mt < 2; mt++)
#pragma unroll
        for (int nt = 0; nt < 8; nt++)
#pragma unroll
            for (int e = 0; e < 4; e++) {
                const int q = q0 + mt * 16 + lg * 4 + e;
                const int k = w * 128 + nt * 16 + lr;
                const int fk = (int)ft[q - k + 511];
                float v = acc[mt][nt][e]
                        + bits2f(c2pb[(long)q * POSN + fk])
                        + bits2f(p2cb[(long)k * POSN + fk]);
                acc[mt][nt][e] = v * SCALE_F;
            }

    // softmax: per-wave row max -> cross-wave max
#pragma unroll
    for (int mt = 0; mt < 2; mt++)
#pragma unroll
        for (int e = 0; e < 4; e++) {
            float m = acc[mt][0][e];
#pragma unroll
            for (int nt = 1; nt < 8; nt++) m = fmaxf(m, acc[mt][nt][e]);
            m = fmaxf(m, __shfl_xor(m, 1));
            m = fmaxf(m, __shfl_xor(m, 2));
            m = fmaxf(m, __shfl_xor(m, 4));
            m = fmaxf(m, __shfl_xor(m, 8));
            red[0][w][mt * 16 + lg * 4 + e] = m;
        }
    __syncthreads();
#pragma unroll
    for (int mt = 0; mt < 2; mt++)
#pragma unroll
        for (int e = 0; e < 4; e++) {
            const int r = mt * 16 + lg * 4 + e;
            float m = fmaxf(fmaxf(red[0][0][r], red[0][1][r]),
                            fmaxf(red[0][2][r], red[0][3][r]));
            float s = 0.f;
#pragma unroll
            for (int nt = 0; nt < 8; nt++) {
                float p = __expf(acc[mt][nt][e] - m);
                acc[mt][nt][e] = p;
                s += p;
            }
            s += __shfl_xor(s, 1); s += __shfl_xor(s, 2);
            s += __shfl_xor(s, 4); s += __shfl_xor(s, 8);
            red[1][w][r] = s;
        }
    __syncthreads();
#pragma unroll
    for (int mt = 0; mt < 2; mt++)
#pragma unroll
        for (int e = 0; e < 4; e++) {
            const int r = mt * 16 + lg * 4 + e;
            rowS[r] = red[1][0][r] + red[1][1][r] + red[1][2][r] + red[1][3][r];
#pragma unroll
            for (int nt = 0; nt < 8; nt++) {
                const int kcol = w * 128 + nt * 16 + lr;
                int byte = r * 1024 + kcol * 2;
                byte ^= (r & 7) << 4;
                *(short*)((char*)Pl + byte) = f2bits(acc[mt][nt][e]);
            }
        }
    __syncthreads();

    // PV: wave w covers its own k range [w*128, w*128+128)
    floatx4 acc2[2][4];
#pragma unroll
    for (int mt = 0; mt < 2; mt++)
#pragma unroll
        for (int nt = 0; nt < 4; nt++) acc2[mt][nt] = (floatx4){0.f, 0.f, 0.f, 0.f};

#pragma unroll
    for (int kk = 0; kk < 4; kk++) {
        short8 pa[2];
#pragma unroll
        for (int mt = 0; mt < 2; mt++) {
            const int qr = mt * 16 + lr;
            int byte = qr * 1024 + (w * 128 + kk * 32 + lg * 8) * 2;
            byte ^= (qr & 7) << 4;
            pa[mt] = *(const short8*)((char*)Pl + byte);
        }
#pragma unroll
        for (int nt = 0; nt < 4; nt++) {
            const int d = nt * 16 + lr;
            const int kg = w * 128 + kk * 32 + lg * 8;
            short8 vb;
#pragma unroll
            for (int i = 0; i < 8; i++) vb[i] = Vb[(kg + i) * 64 + d];
#pragma unroll
            for (int mt = 0; mt < 2; mt++)
                acc2[mt][nt] = __builtin_amdgcn_mfma_f32_16x16x32_bf16(pa[mt], vb, acc2[mt][nt], 0, 0, 0);
        }
    }
#pragma unroll
    for (int mt = 0; mt < 2; mt++)
#pragma unroll
        for (int nt = 0; nt < 4; nt++)
#pragma unroll
            for (int e = 0; e < 4; e++) {
                const int qr = mt * 16 + lg * 4 + e;
                const int d = nt * 16 + lr;
                atomicAdd(&attnred[qr][d], acc2[mt][nt][e]);
            }
    __syncthreads();
    const int b = bh >> 4, h = bh & 15;
    for (int i = t; i < 2048; i += 256) {
        const int qr = i >> 6, d = i & 63;
        float v = attnred[qr][d] / rowS[qr];
        attnO[((long)(b * SEQ + q0 + qr)) * HIDDEN + h * HEAD_DIM + d] = f2bits(v);
    }
}

// ---------------------------------------------------------------------------
extern "C" void kernel_launch(void* const* d_in, const int* in_sizes, int n_in,
                              void* d_out, int out_size, void* d_ws, size_t ws_size,
                              hipStream_t stream)
{
    const float* inputs = (const float*)d_in[0];
    const float* rel    = (const float*)d_in[1];
    const float* Wq     = (const float*)d_in[2];
    const float* bq     = (const float*)d_in[3];
    const float* Wk     = (const float*)d_in[4];
    const float* bk     = (const float*)d_in[5];
    const float* Wv     = (const float*)d_in[6];
    const float* bv     = (const float*)d_in[7];
    const float* Wo     = (const float*)d_in[8];
    const float* bo     = (const float*)d_in[9];
    float* out = (float*)d_out;

    char* ws = (char*)d_ws;
    size_t off = 0;
    auto alloc = [&](size_t bytes) -> char* {
        char* p = ws + off;
        off += (bytes + 255) & ~(size_t)255;
        return p;
    };
    short* inA   = (short*)alloc(4194304ull * 2);
    short* inRel = (short*)alloc(4194304ull * 2);
    short* WqT   = (short*)alloc(1048576ull * 2);
    short* WkT   = (short*)alloc(1048576ull * 2);
    short* WvT   = (short*)alloc(1048576ull * 2);
    short* WoT   = (short*)alloc(1048576ull * 2);
    short* Qw    = (short*)alloc(4194304ull * 2);
    short* Kw    = (short*)alloc(4194304ull * 2);
    short* Vw    = (short*)alloc(4194304ull * 2);
    short* posQw = (short*)alloc(4194304ull * 2);
    short* posKw = (short*)alloc(4194304ull * 2);
    short* c2pW  = (short*)alloc(33554432ull * 2);
    short* p2cW  = (short*)alloc(33554432ull * 2);
    short* attnW = (short*)alloc(4194304ull * 2);
    int*   ftabW = (int*)alloc(4096);

    // prep
    conv_pair<<<4096, 256, 0, stream>>>(inputs, rel, inA, inRel);
    wtrans<<<dim3(16, 16, 4), 256, 0, stream>>>(Wq, Wk, Wv, Wo, WqT, WkT, WvT, WoT);
    ftab_build<<<4, 256, 0, stream>>>(ftabW);

    // projections: Q,K,V from inputs; posQ,posK from rel_embeddings
    dim3 gp(32, 8, 1);
    gemm_nt<0><<<gp, 256, 0, stream>>>(inA,   0, 1024, WqT, 0, 1024, Qw,    0, 0, bq, 1024);
    gemm_nt<0><<<gp, 256, 0, stream>>>(inA,   0, 1024, WkT, 0, 1024, Kw,    0, 0, bk, 1024);
    gemm_nt<0><<<gp, 256, 0, stream>>>(inA,   0, 1024, WvT, 0, 1024, Vw,    0, 0, bv, 1024);
    gemm_nt<0><<<gp, 256, 0, stream>>>(inRel, 0, 1024, WqT, 0, 1024, posQw, 0, 0, bq, 1024);
    gemm_nt<0><<<gp, 256, 0, stream>>>(inRel, 0, 1024, WkT, 0, 1024, posKw, 0, 0, bk, 1024);

    // c2pfull = Q @ posK^T, p2cfull = K @ posQ^T  (batched over 128 (b,h))
    dim3 gs(4, 4, 128);
    gemm_nt<1><<<gs, 256, 0, stream>>>(Qw, 32768, 64, posKw, 32768, 64, c2pW, 262144, 512, nullptr, 64);
    gemm_nt<1><<<gs, 256, 0, stream>>>(Kw, 32768, 64, posQw, 32768, 64, p2cW, 262144, 512, nullptr, 64);

    // fused scores+gather+softmax+PV
    attn_fused<<<dim3(16, 128), 256, 0, stream>>>(Qw, Kw, Vw, c2pW, p2cW, ftabW, attnW);

    // output projection (fp32 out + bias)
    gemm_nt<2><<<gp, 256, 0, stream>>>(attnW, 0, 1024, WoT, 0, 1024, out, 0, 1024, bo, 1024);
}

// Round 2
// 358.843 us; speedup vs baseline: 1.0138x; 1.0138x over previous
//
#include <hip/hip_runtime.h>

#define NUM_HEADS 16
#define HEAD_DIM  64
#define HIDDEN    1024
#define SEQ       512
#define BATCH     8
#define NBH       128      // BATCH*NUM_HEADS
#define POSN      512      // 2*BUCKET
#define SCALE_F   0.07216878364870323f   // 1/sqrt(3*HEAD_DIM)

typedef __attribute__((ext_vector_type(8))) short  short8;
typedef __attribute__((ext_vector_type(4))) short  short4_t;
typedef __attribute__((ext_vector_type(4))) float  floatx4;

__device__ __forceinline__ float bits2f(short s) {
    union { unsigned u; float f; } x;
    x.u = ((unsigned)(unsigned short)s) << 16;
    return x.f;
}
__device__ __forceinline__ short f2bits(float f) {
    union { float f; unsigned u; } x;
    x.f = f;
    unsigned r = x.u + 0x7fffu + ((x.u >> 16) & 1u);
    return (short)(r >> 16);
}

// ---------------------------------------------------------------------------
// prep: fp32 -> bf16 conversion for inputs and rel_embeddings
// ---------------------------------------------------------------------------
__global__ void conv_pair(const float* __restrict__ a, const float* __restrict__ b,
                          short* __restrict__ oa, short* __restrict__ ob)
{
    const int idx = blockIdx.x * 256 + threadIdx.x;    // one float4 each
    floatx4 va = ((const floatx4*)a)[idx];
    floatx4 vb = ((const floatx4*)b)[idx];
    short4_t ra, rb;
#pragma unroll
    for (int i = 0; i < 4; i++) { ra[i] = f2bits(va[i]); rb[i] = f2bits(vb[i]); }
    ((short4_t*)oa)[idx] = ra;
    ((short4_t*)ob)[idx] = rb;
}

// ---------------------------------------------------------------------------
// prep: transpose + convert the 4 weight matrices [1024][1024] -> bf16 [n][c]
// ---------------------------------------------------------------------------
__global__ void wtrans(const float* __restrict__ w0, const float* __restrict__ w1,
                       const float* __restrict__ w2, const float* __restrict__ w3,
                       short* __restrict__ o0, short* __restrict__ o1,
                       short* __restrict__ o2, short* __restrict__ o3)
{
    __shared__ float tile[64][65];
    const int z = blockIdx.z;
    const float* src = (z == 0) ? w0 : (z == 1) ? w1 : (z == 2) ? w2 : w3;
    short*       dst = (z == 0) ? o0 : (z == 1) ? o1 : (z == 2) ? o2 : o3;
    const int c0 = blockIdx.x * 64, n0 = blockIdx.y * 64;
    const int t = threadIdx.x;
#pragma unroll
    for (int j = 0; j < 16; j++) {
        const int e = t + j * 256;
        tile[e >> 6][e & 63] = src[(long)(c0 + (e >> 6)) * 1024 + n0 + (e & 63)];
    }
    __syncthreads();
#pragma unroll
    for (int j = 0; j < 16; j++) {
        const int e = t + j * 256;
        dst[(long)(n0 + (e >> 6)) * 1024 + c0 + (e & 63)] = f2bits(tile[e & 63][e >> 6]);
    }
}

// ---------------------------------------------------------------------------
// prep: 1-D log-bucket table  ftab[delta+511] = clip(bucket(delta)+256, 0, 511)
// ---------------------------------------------------------------------------
__global__ void ftab_build(int* __restrict__ ftab)
{
    const int i = blockIdx.x * 256 + threadIdx.x;
    if (i >= 1023) return;
    const int delta = i - 511;
    const float Cf = (float)log(511.0 / 128.0);
    float absp = (delta < 128 && delta > -128) ? 127.0f : fabsf((float)delta);
    float bucket;
    if (absp <= 128.0f) {
        bucket = (float)delta;
    } else {
        float lp = ceilf((logf(absp * (1.0f / 128.0f)) * 127.0f) / Cf) + 128.0f;
        bucket = (delta > 0) ? lp : -lp;
    }
    int bi = (int)bucket + 256;
    bi = min(max(bi, 0), 511);
    ftab[i] = bi;
}

// ---------------------------------------------------------------------------
// Generic NT GEMM: C[m,n] = sum_k A[m,k] * BT[n,k]   (bf16 in, fp32 acc)
// tile 128x128, BK=64, 256 threads (4 waves, 2x2), 16x16x32 bf16 MFMA
// MODE 0: proj  -> bf16 out laid out [b,h,s,d], + bias[n]
// MODE 1: plain -> bf16 out row-major [m*ldo+n], batched by z
// MODE 2: final -> fp32 out row-major + bias[n]
// MODE 3: V-proj -> bf16 out laid out [b,h,d,s] (transposed), + bias[n]
// ---------------------------------------------------------------------------
template<int MODE>
__global__ __launch_bounds__(256)
void gemm_nt(const short* __restrict__ A, long aBatch, int lda,
             const short* __restrict__ BT, long bBatch, int ldb,
             void* __restrict__ OutP, long oBatch, int ldo,
             const float* __restrict__ bias, int Kd)
{
    __shared__ __align__(16) short As[128 * 64];
    __shared__ __align__(16) short Bs[128 * 64];
    const int z = blockIdx.z;
    const short* Ab = A + (long)z * aBatch;
    const short* Bb = BT + (long)z * bBatch;
    const int m0 = blockIdx.x * 128, n0 = blockIdx.y * 128;
    const int t = threadIdx.x;
    const int l = t & 63, w = t >> 6;
    const int wm = w >> 1, wn = w & 1;
    const int lr = l & 15, lg = l >> 4;

    floatx4 acc[4][4];
#pragma unroll
    for (int i = 0; i < 4; i++)
#pragma unroll
        for (int j = 0; j < 4; j++) acc[i][j] = (floatx4){0.f, 0.f, 0.f, 0.f};

    for (int k0 = 0; k0 < Kd; k0 += 64) {
        __syncthreads();
#pragma unroll
        for (int j = 0; j < 4; j++) {
            const int chunk = t + j * 256;   // 1024 chunks of 16B per matrix
            const int row = chunk >> 3;      // 0..127
            const int cc  = chunk & 7;       // logical 16B chunk in row
            const int pc  = cc ^ (row & 7);  // XOR swizzle (bank-conflict-free reads)
            short8 va = *(const short8*)(Ab + (long)(m0 + row) * lda + k0 + cc * 8);
            *(short8*)((char*)As + row * 128 + pc * 16) = va;
            short8 vb = *(const short8*)(Bb + (long)(n0 + row) * ldb + k0 + cc * 8);
            *(short8*)((char*)Bs + row * 128 + pc * 16) = vb;
        }
        __syncthreads();
#pragma unroll
        for (int ks = 0; ks < 2; ks++) {
            short8 af[4], bfr[4];
#pragma unroll
            for (int i = 0; i < 4; i++) {
                const int mr = wm * 64 + i * 16 + lr;
                af[i] = *(const short8*)((char*)As + mr * 128 + (((ks * 4 + lg) ^ (mr & 7)) * 16));
                const int nr = wn * 64 + i * 16 + lr;
                bfr[i] = *(const short8*)((char*)Bs + nr * 128 + (((ks * 4 + lg) ^ (nr & 7)) * 16));
            }
#pragma unroll
            for (int i = 0; i < 4; i++)
#pragma unroll
                for (int j = 0; j < 4; j++)
                    acc[i][j] = __builtin_amdgcn_mfma_f32_16x16x32_bf16(af[i], bfr[j], acc[i][j], 0, 0, 0);
        }
    }

#pragma unroll
    for (int i = 0; i < 4; i++) {
#pragma unroll
        for (int j = 0; j < 4; j++) {
#pragma unroll
            for (int e = 0; e < 4; e++) {
                const int mg = m0 + wm * 64 + i * 16 + lg * 4 + e;
                const int ng = n0 + wn * 64 + j * 16 + lr;
                float v = acc[i][j][e];
                if (MODE == 0) {
                    v += bias[ng];
                    const int b = mg >> 9, s = mg & 511, h = ng >> 6, d = ng & 63;
                    ((short*)OutP)[((long)(b * NUM_HEADS + h) * SEQ + s) * HEAD_DIM + d] = f2bits(v);
                } else if (MODE == 1) {
                    ((short*)OutP)[(long)z * oBatch + (long)mg * ldo + ng] = f2bits(v);
                } else if (MODE == 2) {
                    ((float*)OutP)[(long)mg * ldo + ng] = v + bias[ng];
                } else {
                    v += bias[ng];
                    const int b = mg >> 9, s = mg & 511, h = ng >> 6, d = ng & 63;
                    ((short*)OutP)[((long)(b * NUM_HEADS + h) * HEAD_DIM + d) * SEQ + s] = f2bits(v);
                }
            }
        }
    }
}

// ---------------------------------------------------------------------------
// Fused attention per (b,h, 32-row q-tile):
//   stage c2p q-rows in LDS (swizzled, shares buffer with P-tile);
//   prefetch p2cT gathers to regs; QK^T (MFMA from global/L2);
//   add gathered c2p/p2c; row softmax; P->LDS (swizzled); PV (MFMA, Vt 16B
//   vector loads); cross-wave reduce; normalize; write bf16 [b*s][h*64+d].
// 4 waves; wave w owns score columns [w*128, w*128+128).
// ---------------------------------------------------------------------------
__global__ __launch_bounds__(256)
void attn_fused(const short* __restrict__ Q, const short* __restrict__ K,
                const short* __restrict__ Vt,
                const short* __restrict__ c2pf, const short* __restrict__ p2cT,
                const int* __restrict__ ftab,
                short* __restrict__ attnO)
{
    __shared__ __align__(16) short PS[32 * 512];   // phase 1: staged c2p rows; phase 2: P tile
    __shared__ float red[2][4][32];
    __shared__ float rowS[32];
    __shared__ float attnred[32][64];
    __shared__ short ft[1024];

    const int qt = blockIdx.x, bh = blockIdx.y;
    const int q0 = qt * 32;
    const int t = threadIdx.x, l = t & 63, w = t >> 6;
    const int lr = l & 15, lg = l >> 4;
    const long pbase = (long)bh * SEQ * HEAD_DIM;
    const short* Qb  = Q  + pbase;
    const short* Kb  = K  + pbase;
    const short* Vtb = Vt + pbase;
    const long sbase = (long)bh * SEQ * POSN;
    const short* c2pb  = c2pf + sbase;
    const short* p2cTb = p2cT + sbase;

    // ---- staging phase ----
    for (int i = t; i < 1024; i += 256) ft[i] = (short)((i < 1023) ? ftab[i] : 0);
    for (int i = t; i < 2048; i += 256) ((float*)attnred)[i] = 0.f;
    // stage the block's 32 c2p rows, swizzled so gathers are bank-spread:
    // element index fk is XOR'd with ((row>>2)&3)<<4  -> chunk ^= ((row>>2)&3)<<1
#pragma unroll
    for (int j = 0; j < 8; j++) {
        const int chunk = t + j * 256;     // 0..2047 (8-elem chunks)
        const int row = chunk >> 6;        // 0..31
        const int cc  = chunk & 63;
        const int pc  = cc ^ (((row >> 2) & 3) << 1);
        short8 v = *(const short8*)(c2pb + (long)(q0 + row) * POSN + cc * 8);
        *(short8*)(PS + row * 512 + pc * 8) = v;
    }
    __syncthreads();

    // ---- prefetch p2c gathers (coalesced 32B per 16-lane group) ----
    short p2cv[2][8][4];
#pragma unroll
    for (int mt = 0; mt < 2; mt++)
#pragma unroll
        for (int nt = 0; nt < 8; nt++)
#pragma unroll
            for (int e = 0; e < 4; e++) {
                const int q = q0 + mt * 16 + lg * 4 + e;
                const int k = w * 128 + nt * 16 + lr;
                const int fk = (int)ft[q - k + 511];
                p2cv[mt][nt][e] = p2cTb[(long)fk * POSN + k];
            }

    // ---- Q fragments ----
    short8 aq[2][2];
#pragma unroll
    for (int mt = 0; mt < 2; mt++)
#pragma unroll
        for (int ks = 0; ks < 2; ks++)
            aq[mt][ks] = *(const short8*)(Qb + (q0 + mt * 16 + lr) * 64 + ks * 32 + lg * 8);

    floatx4 acc[2][8];
#pragma unroll
    for (int mt = 0; mt < 2; mt++)
#pragma unroll
        for (int nt = 0; nt < 8; nt++) acc[mt][nt] = (floatx4){0.f, 0.f, 0.f, 0.f};

    // ---- QK^T ----
#pragma unroll
    for (int nt = 0; nt < 8; nt++) {
        const int kr = w * 128 + nt * 16 + lr;
        short8 kb0 = *(const short8*)(Kb + kr * 64 + lg * 8);
        short8 kb1 = *(const short8*)(Kb + kr * 64 + 32 + lg * 8);
#pragma unroll
        for (int mt = 0; mt < 2; mt++) {
            acc[mt][nt] = __builtin_amdgcn_mfma_f32_16x16x32_bf16(aq[mt][0], kb0, acc[mt][nt], 0, 0, 0);
            acc[mt][nt] = __builtin_amdgcn_mfma_f32_16x16x32_bf16(aq[mt][1], kb1, acc[mt][nt], 0, 0, 0);
        }
    }

    // ---- add gathered c2p (LDS) + p2c (regs), scale ----
#pragma unroll
    for (int mt = 0; mt < 2; mt++)
#pragma unroll
        for (int nt = 0; nt < 8; nt++)
#pragma unroll
            for (int e = 0; e < 4; e++) {
                const int qr = mt * 16 + lg * 4 + e;
                const int k = w * 128 + nt * 16 + lr;
                const int fk = (int)ft[q0 + qr - k + 511];
                float v = acc[mt][nt][e]
                        + bits2f(PS[qr * 512 + (fk ^ (lg << 4))])
                        + bits2f(p2cv[mt][nt][e]);
                acc[mt][nt][e] = v * SCALE_F;
            }

    // ---- softmax: per-wave row max -> cross-wave max ----
#pragma unroll
    for (int mt = 0; mt < 2; mt++)
#pragma unroll
        for (int e = 0; e < 4; e++) {
            float m = acc[mt][0][e];
#pragma unroll
            for (int nt = 1; nt < 8; nt++) m = fmaxf(m, acc[mt][nt][e]);
            m = fmaxf(m, __shfl_xor(m, 1));
            m = fmaxf(m, __shfl_xor(m, 2));
            m = fmaxf(m, __shfl_xor(m, 4));
            m = fmaxf(m, __shfl_xor(m, 8));
            red[0][w][mt * 16 + lg * 4 + e] = m;
        }
    __syncthreads();
#pragma unroll
    for (int mt = 0; mt < 2; mt++)
#pragma unroll
        for (int e = 0; e < 4; e++) {
            const int r = mt * 16 + lg * 4 + e;
            float m = fmaxf(fmaxf(red[0][0][r], red[0][1][r]),
                            fmaxf(red[0][2][r], red[0][3][r]));
            float s = 0.f;
#pragma unroll
            for (int nt = 0; nt < 8; nt++) {
                float p = __expf(acc[mt][nt][e] - m);
                acc[mt][nt][e] = p;
                s += p;
            }
            s += __shfl_xor(s, 1); s += __shfl_xor(s, 2);
            s += __shfl_xor(s, 4); s += __shfl_xor(s, 8);
            red[1][w][r] = s;
        }
    __syncthreads();
    // ---- write P tile (overwrites c2p staging; safe: all c2p reads done) ----
#pragma unroll
    for (int mt = 0; mt < 2; mt++)
#pragma unroll
        for (int e = 0; e < 4; e++) {
            const int r = mt * 16 + lg * 4 + e;
            rowS[r] = red[1][0][r] + red[1][1][r] + red[1][2][r] + red[1][3][r];
#pragma unroll
            for (int nt = 0; nt < 8; nt++) {
                const int kcol = w * 128 + nt * 16 + lr;
                int byte = r * 1024 + kcol * 2;
                byte ^= (r & 7) << 4;
                *(short*)((char*)PS + byte) = f2bits(acc[mt][nt][e]);
            }
        }
    __syncthreads();

    // ---- PV: wave w covers k range [w*128, w*128+128), Vt gives 16B loads ----
    floatx4 acc2[2][4];
#pragma unroll
    for (int mt = 0; mt < 2; mt++)
#pragma unroll
        for (int nt = 0; nt < 4; nt++) acc2[mt][nt] = (floatx4){0.f, 0.f, 0.f, 0.f};

#pragma unroll
    for (int kk = 0; kk < 4; kk++) {
        short8 pa[2];
#pragma unroll
        for (int mt = 0; mt < 2; mt++) {
            const int qr = mt * 16 + lr;
            int byte = qr * 1024 + (w * 128 + kk * 32 + lg * 8) * 2;
            byte ^= (qr & 7) << 4;
            pa[mt] = *(const short8*)((char*)PS + byte);
        }
        const int kg = w * 128 + kk * 32 + lg * 8;
#pragma unroll
        for (int nt = 0; nt < 4; nt++) {
            const int d = nt * 16 + lr;
            short8 vb = *(const short8*)(Vtb + (long)d * SEQ + kg);
#pragma unroll
            for (int mt = 0; mt < 2; mt++)
                acc2[mt][nt] = __builtin_amdgcn_mfma_f32_16x16x32_bf16(pa[mt], vb, acc2[mt][nt], 0, 0, 0);
        }
    }
#pragma unroll
    for (int mt = 0; mt < 2; mt++)
#pragma unroll
        for (int nt = 0; nt < 4; nt++)
#pragma unroll
            for (int e = 0; e < 4; e++) {
                const int qr = mt * 16 + lg * 4 + e;
                const int d = nt * 16 + lr;
                atomicAdd(&attnred[qr][d], acc2[mt][nt][e]);
            }
    __syncthreads();
    const int b = bh >> 4, h = bh & 15;
    for (int i = t; i < 2048; i += 256) {
        const int qr = i >> 6, d = i & 63;
        float v = attnred[qr][d] / rowS[qr];
        attnO[((long)(b * SEQ + q0 + qr)) * HIDDEN + h * HEAD_DIM + d] = f2bits(v);
    }
}

// ---------------------------------------------------------------------------
extern "C" void kernel_launch(void* const* d_in, const int* in_sizes, int n_in,
                              void* d_out, int out_size, void* d_ws, size_t ws_size,
                              hipStream_t stream)
{
    const float* inputs = (const float*)d_in[0];
    const float* rel    = (const float*)d_in[1];
    const float* Wq     = (const float*)d_in[2];
    const float* bq     = (const float*)d_in[3];
    const float* Wk     = (const float*)d_in[4];
    const float* bk     = (const float*)d_in[5];
    const float* Wv     = (const float*)d_in[6];
    const float* bv     = (const float*)d_in[7];
    const float* Wo     = (const float*)d_in[8];
    const float* bo     = (const float*)d_in[9];
    float* out = (float*)d_out;

    char* ws = (char*)d_ws;
    size_t off = 0;
    auto alloc = [&](size_t bytes) -> char* {
        char* p = ws + off;
        off += (bytes + 255) & ~(size_t)255;
        return p;
    };
    short* inA   = (short*)alloc(4194304ull * 2);
    short* inRel = (short*)alloc(4194304ull * 2);
    short* WqT   = (short*)alloc(1048576ull * 2);
    short* WkT   = (short*)alloc(1048576ull * 2);
    short* WvT   = (short*)alloc(1048576ull * 2);
    short* WoT   = (short*)alloc(1048576ull * 2);
    short* Qw    = (short*)alloc(4194304ull * 2);
    short* Kw    = (short*)alloc(4194304ull * 2);
    short* Vtw   = (short*)alloc(4194304ull * 2);
    short* posQw = (short*)alloc(4194304ull * 2);
    short* posKw = (short*)alloc(4194304ull * 2);
    short* c2pW  = (short*)alloc(33554432ull * 2);
    short* p2cW  = (short*)alloc(33554432ull * 2);
    short* attnW = (short*)alloc(4194304ull * 2);
    int*   ftabW = (int*)alloc(4096);

    // prep
    conv_pair<<<4096, 256, 0, stream>>>(inputs, rel, inA, inRel);
    wtrans<<<dim3(16, 16, 4), 256, 0, stream>>>(Wq, Wk, Wv, Wo, WqT, WkT, WvT, WoT);
    ftab_build<<<4, 256, 0, stream>>>(ftabW);

    // projections: Q,K from inputs; V transposed; posQ,posK from rel_embeddings
    dim3 gp(32, 8, 1);
    gemm_nt<0><<<gp, 256, 0, stream>>>(inA,   0, 1024, WqT, 0, 1024, Qw,    0, 0, bq, 1024);
    gemm_nt<0><<<gp, 256, 0, stream>>>(inA,   0, 1024, WkT, 0, 1024, Kw,    0, 0, bk, 1024);
    gemm_nt<3><<<gp, 256, 0, stream>>>(inA,   0, 1024, WvT, 0, 1024, Vtw,   0, 0, bv, 1024);
    gemm_nt<0><<<gp, 256, 0, stream>>>(inRel, 0, 1024, WqT, 0, 1024, posQw, 0, 0, bq, 1024);
    gemm_nt<0><<<gp, 256, 0, stream>>>(inRel, 0, 1024, WkT, 0, 1024, posKw, 0, 0, bk, 1024);

    // c2pfull = Q @ posK^T  [q,p];  p2cT = posQ @ K^T  [p,k]  (batched over bh)
    dim3 gs(4, 4, 128);
    gemm_nt<1><<<gs, 256, 0, stream>>>(Qw,    32768, 64, posKw, 32768, 64, c2pW, 262144, 512, nullptr, 64);
    gemm_nt<1><<<gs, 256, 0, stream>>>(posQw, 32768, 64, Kw,    32768, 64, p2cW, 262144, 512, nullptr, 64);

    // fused scores+gather+softmax+PV
    attn_fused<<<dim3(16, 128), 256, 0, stream>>>(Qw, Kw, Vtw, c2pW, p2cW, ftabW, attnW);

    // output projection (fp32 out + bias)
    gemm_nt<2><<<gp, 256, 0, stream>>>(attnW, 0, 1024, WoT, 0, 1024, out, 0, 1024, bo, 1024);
}

// Round 3
// 247.199 us; speedup vs baseline: 1.4717x; 1.4516x over previous
//
#include <hip/hip_runtime.h>

#define NUM_HEADS 16
#define HEAD_DIM  64
#define HIDDEN    1024
#define SEQ       512
#define BATCH     8
#define NBH       128      // BATCH*NUM_HEADS
#define POSN      512      // 2*BUCKET
#define SCALE_F   0.07216878364870323f   // 1/sqrt(3*HEAD_DIM)

typedef __attribute__((ext_vector_type(8))) short  short8;
typedef __attribute__((ext_vector_type(4))) short  short4_t;
typedef __attribute__((ext_vector_type(4))) float  floatx4;

__device__ __forceinline__ float bits2f(short s) {
    union { unsigned u; float f; } x;
    x.u = ((unsigned)(unsigned short)s) << 16;
    return x.f;
}
__device__ __forceinline__ float lo2f(unsigned u) {
    union { unsigned u; float f; } x; x.u = u << 16; return x.f;
}
__device__ __forceinline__ float hi2f(unsigned u) {
    union { unsigned u; float f; } x; x.u = u & 0xffff0000u; return x.f;
}
__device__ __forceinline__ short f2bits(float f) {
    union { float f; unsigned u; } x;
    x.f = f;
    unsigned r = x.u + 0x7fffu + ((x.u >> 16) & 1u);
    return (short)(r >> 16);
}

// ---------------------------------------------------------------------------
// prep: fp32 -> bf16 conversion for inputs and rel_embeddings
// ---------------------------------------------------------------------------
__global__ void conv_pair(const float* __restrict__ a, const float* __restrict__ b,
                          short* __restrict__ oa, short* __restrict__ ob)
{
    const int idx = blockIdx.x * 256 + threadIdx.x;    // one float4 each
    floatx4 va = ((const floatx4*)a)[idx];
    floatx4 vb = ((const floatx4*)b)[idx];
    short4_t ra, rb;
#pragma unroll
    for (int i = 0; i < 4; i++) { ra[i] = f2bits(va[i]); rb[i] = f2bits(vb[i]); }
    ((short4_t*)oa)[idx] = ra;
    ((short4_t*)ob)[idx] = rb;
}

// ---------------------------------------------------------------------------
// prep: transpose + convert the 4 weight matrices [1024][1024] -> bf16 [n][c]
// (o0..o3 are contiguous in ws, so o0 doubles as concat(WqT,WkT,WvT))
// ---------------------------------------------------------------------------
__global__ void wtrans(const float* __restrict__ w0, const float* __restrict__ w1,
                       const float* __restrict__ w2, const float* __restrict__ w3,
                       short* __restrict__ o0, short* __restrict__ o1,
                       short* __restrict__ o2, short* __restrict__ o3)
{
    __shared__ float tile[64][65];
    const int z = blockIdx.z;
    const float* src = (z == 0) ? w0 : (z == 1) ? w1 : (z == 2) ? w2 : w3;
    short*       dst = (z == 0) ? o0 : (z == 1) ? o1 : (z == 2) ? o2 : o3;
    const int c0 = blockIdx.x * 64, n0 = blockIdx.y * 64;
    const int t = threadIdx.x;
#pragma unroll
    for (int j = 0; j < 16; j++) {
        const int e = t + j * 256;
        tile[e >> 6][e & 63] = src[(long)(c0 + (e >> 6)) * 1024 + n0 + (e & 63)];
    }
    __syncthreads();
#pragma unroll
    for (int j = 0; j < 16; j++) {
        const int e = t + j * 256;
        dst[(long)(n0 + (e >> 6)) * 1024 + c0 + (e & 63)] = f2bits(tile[e & 63][e >> 6]);
    }
}

// ---------------------------------------------------------------------------
// prep: 1-D log-bucket table  ftab[delta+511] = clip(bucket(delta)+256, 0, 511)
// ---------------------------------------------------------------------------
__global__ void ftab_build(int* __restrict__ ftab)
{
    const int i = blockIdx.x * 256 + threadIdx.x;
    if (i >= 1023) return;
    const int delta = i - 511;
    const float Cf = (float)log(511.0 / 128.0);
    float absp = (delta < 128 && delta > -128) ? 127.0f : fabsf((float)delta);
    float bucket;
    if (absp <= 128.0f) {
        bucket = (float)delta;
    } else {
        float lp = ceilf((logf(absp * (1.0f / 128.0f)) * 127.0f) / Cf) + 128.0f;
        bucket = (delta > 0) ? lp : -lp;
    }
    int bi = (int)bucket + 256;
    bi = min(max(bi, 0), 511);
    ftab[i] = bi;
}

// ---------------------------------------------------------------------------
// Generic NT GEMM: C[m,n] = sum_k A[m,k] * BT[n,k]   (bf16 in, fp32 acc)
// tile 128x128, BK=64, 256 threads (4 waves, 2x2), 16x16x32 bf16 MFMA
// MODE 1: plain -> bf16 out row-major [m*ldo+n], batched by z (O0)
// MODE 2: final -> fp32 out row-major + bias b0 (O0)
// MODE 4: QKV   -> n<1024: Q [b,h,s,d]+b0 (O0); n<2048: K +b1 (O1);
//                  else:   V [b,h,d,s]+b2 (O2)
// MODE 5: posQK -> n<1024: posQ [b,h,p,d]+b0 (O0); else posK +b1 (O1)
// ---------------------------------------------------------------------------
template<int MODE>
__global__ __launch_bounds__(256)
void gemm_nt(const short* __restrict__ A, long aBatch, int lda,
             const short* __restrict__ BT, long bBatch, int ldb,
             void* __restrict__ O0, void* __restrict__ O1, void* __restrict__ O2,
             long oBatch, int ldo,
             const float* __restrict__ b0, const float* __restrict__ b1,
             const float* __restrict__ b2, int Kd)
{
    __shared__ __align__(16) short As[128 * 64];
    __shared__ __align__(16) short Bs[128 * 64];
    const int z = blockIdx.z;
    const short* Ab = A + (long)z * aBatch;
    const short* Bb = BT + (long)z * bBatch;
    const int m0 = blockIdx.x * 128, n0 = blockIdx.y * 128;
    const int t = threadIdx.x;
    const int l = t & 63, w = t >> 6;
    const int wm = w >> 1, wn = w & 1;
    const int lr = l & 15, lg = l >> 4;

    floatx4 acc[4][4];
#pragma unroll
    for (int i = 0; i < 4; i++)
#pragma unroll
        for (int j = 0; j < 4; j++) acc[i][j] = (floatx4){0.f, 0.f, 0.f, 0.f};

    for (int k0 = 0; k0 < Kd; k0 += 64) {
        __syncthreads();
#pragma unroll
        for (int j = 0; j < 4; j++) {
            const int chunk = t + j * 256;   // 1024 chunks of 16B per matrix
            const int row = chunk >> 3;      // 0..127
            const int cc  = chunk & 7;       // logical 16B chunk in row
            const int pc  = cc ^ (row & 7);  // XOR swizzle (bank-conflict-free reads)
            short8 va = *(const short8*)(Ab + (long)(m0 + row) * lda + k0 + cc * 8);
            *(short8*)((char*)As + row * 128 + pc * 16) = va;
            short8 vb = *(const short8*)(Bb + (long)(n0 + row) * ldb + k0 + cc * 8);
            *(short8*)((char*)Bs + row * 128 + pc * 16) = vb;
        }
        __syncthreads();
#pragma unroll
        for (int ks = 0; ks < 2; ks++) {
            short8 af[4], bfr[4];
#pragma unroll
            for (int i = 0; i < 4; i++) {
                const int mr = wm * 64 + i * 16 + lr;
                af[i] = *(const short8*)((char*)As + mr * 128 + (((ks * 4 + lg) ^ (mr & 7)) * 16));
                const int nr = wn * 64 + i * 16 + lr;
                bfr[i] = *(const short8*)((char*)Bs + nr * 128 + (((ks * 4 + lg) ^ (nr & 7)) * 16));
            }
#pragma unroll
            for (int i = 0; i < 4; i++)
#pragma unroll
                for (int j = 0; j < 4; j++)
                    acc[i][j] = __builtin_amdgcn_mfma_f32_16x16x32_bf16(af[i], bfr[j], acc[i][j], 0, 0, 0);
        }
    }

#pragma unroll
    for (int i = 0; i < 4; i++) {
#pragma unroll
        for (int j = 0; j < 4; j++) {
#pragma unroll
            for (int e = 0; e < 4; e++) {
                const int mg = m0 + wm * 64 + i * 16 + lg * 4 + e;
                const int ng = n0 + wn * 64 + j * 16 + lr;
                float v = acc[i][j][e];
                if (MODE == 1) {
                    ((short*)O0)[(long)z * oBatch + (long)mg * ldo + ng] = f2bits(v);
                } else if (MODE == 2) {
                    ((float*)O0)[(long)mg * ldo + ng] = v + b0[ng];
                } else if (MODE == 4) {
                    const int mat = ng >> 10, hh = ng & 1023, h = hh >> 6, d = hh & 63;
                    const int b = mg >> 9, s = mg & 511;
                    v += (mat == 0 ? b0 : mat == 1 ? b1 : b2)[hh];
                    short* dst = (short*)(mat == 0 ? O0 : mat == 1 ? O1 : O2);
                    if (mat == 2)
                        dst[((long)(b * NUM_HEADS + h) * HEAD_DIM + d) * SEQ + s] = f2bits(v);
                    else
                        dst[((long)(b * NUM_HEADS + h) * SEQ + s) * HEAD_DIM + d] = f2bits(v);
                } else {  // MODE 5
                    const int mat = ng >> 10, hh = ng & 1023, h = hh >> 6, d = hh & 63;
                    const int b = mg >> 9, s = mg & 511;
                    v += (mat == 0 ? b0 : b1)[hh];
                    short* dst = (short*)(mat == 0 ? O0 : O1);
                    dst[((long)(b * NUM_HEADS + h) * SEQ + s) * HEAD_DIM + d] = f2bits(v);
                }
            }
        }
    }
}

// ---------------------------------------------------------------------------
// Fused attention per (b,h, 16-row q-tile). 4 waves, 3 barriers.
//   QK^T: wave w owns k in [w*128, w*128+128); gathers prefetched to packed
//   regs (c2p coalesced 32B/group; p2c diagonal but deep-pipelined).
//   softmax: shfl within 16-lane groups + tiny LDS cross-wave combine.
//   PV: wave w owns OUTPUT dims d in [w*16, w*16+16) -> no cross-wave reduce.
// LDS ~18.8 KB; __launch_bounds__(256,4) -> VGPR<=128 -> 16 waves/CU.
// ---------------------------------------------------------------------------
__global__ __launch_bounds__(256, 4)
void attn_fused(const short* __restrict__ Q, const short* __restrict__ K,
                const short* __restrict__ Vt,
                const short* __restrict__ c2pf, const short* __restrict__ p2cT,
                const int* __restrict__ ftab,
                short* __restrict__ attnO)
{
    __shared__ __align__(16) short PS[16 * 512];   // swizzled P tile
    __shared__ float red[2][4][16];
    __shared__ short ft[1024];

    // XCD-chunked swizzle: blocks of one bh land on one XCD (4096 % 8 == 0)
    const int lin  = blockIdx.x;
    const int lin2 = (lin & 7) * 512 + (lin >> 3);
    const int bh = lin2 >> 5, qt = lin2 & 31;
    const int q0 = qt * 16;
    const int t = threadIdx.x, l = t & 63, w = t >> 6;
    const int lr = l & 15, lg = l >> 4;
    const long pbase = (long)bh * SEQ * HEAD_DIM;
    const short* Qb  = Q  + pbase;
    const short* Kb  = K  + pbase;
    const short* Vtb = Vt + pbase;
    const long sbase = (long)bh * SEQ * POSN;
    const short* c2pb  = c2pf + sbase;
    const short* p2cTb = p2cT + sbase;

    for (int i = t; i < 1024; i += 256) ft[i] = (short)((i < 1023) ? ftab[i] : 0);
    __syncthreads();

    // ---- prefetch gathers into packed u32 regs ----
    unsigned cpk[8][2], ppk[8][2];
#pragma unroll
    for (int nt = 0; nt < 8; nt++) {
        unsigned short cv[4], pv[4];
#pragma unroll
        for (int e = 0; e < 4; e++) {
            const int q = q0 + lg * 4 + e;
            const int k = w * 128 + nt * 16 + lr;
            const int fk = (int)ft[q - k + 511];
            cv[e] = (unsigned short)c2pb[(long)q * POSN + fk];
            pv[e] = (unsigned short)p2cTb[(long)fk * POSN + k];
        }
        cpk[nt][0] = cv[0] | ((unsigned)cv[1] << 16);
        cpk[nt][1] = cv[2] | ((unsigned)cv[3] << 16);
        ppk[nt][0] = pv[0] | ((unsigned)pv[1] << 16);
        ppk[nt][1] = pv[2] | ((unsigned)pv[3] << 16);
    }

    // ---- Q fragments ----
    short8 aq[2];
#pragma unroll
    for (int ks = 0; ks < 2; ks++)
        aq[ks] = *(const short8*)(Qb + (q0 + lr) * 64 + ks * 32 + lg * 8);

    floatx4 acc[8];
#pragma unroll
    for (int nt = 0; nt < 8; nt++) acc[nt] = (floatx4){0.f, 0.f, 0.f, 0.f};

    // ---- QK^T ----
#pragma unroll
    for (int nt = 0; nt < 8; nt++) {
        const int kr = w * 128 + nt * 16 + lr;
        short8 kb0 = *(const short8*)(Kb + kr * 64 + lg * 8);
        short8 kb1 = *(const short8*)(Kb + kr * 64 + 32 + lg * 8);
        acc[nt] = __builtin_amdgcn_mfma_f32_16x16x32_bf16(aq[0], kb0, acc[nt], 0, 0, 0);
        acc[nt] = __builtin_amdgcn_mfma_f32_16x16x32_bf16(aq[1], kb1, acc[nt], 0, 0, 0);
    }

    // ---- add gathers, scale ----
#pragma unroll
    for (int nt = 0; nt < 8; nt++)
#pragma unroll
        for (int e = 0; e < 4; e++) {
            const float cv = (e & 1) ? hi2f(cpk[nt][e >> 1]) : lo2f(cpk[nt][e >> 1]);
            const float pv = (e & 1) ? hi2f(ppk[nt][e >> 1]) : lo2f(ppk[nt][e >> 1]);
            acc[nt][e] = (acc[nt][e] + cv + pv) * SCALE_F;
        }

    // ---- wave-local row max -> LDS ----
#pragma unroll
    for (int e = 0; e < 4; e++) {
        float m = acc[0][e];
#pragma unroll
        for (int nt = 1; nt < 8; nt++) m = fmaxf(m, acc[nt][e]);
        m = fmaxf(m, __shfl_xor(m, 1));
        m = fmaxf(m, __shfl_xor(m, 2));
        m = fmaxf(m, __shfl_xor(m, 4));
        m = fmaxf(m, __shfl_xor(m, 8));
        red[0][w][lg * 4 + e] = m;
    }
    __syncthreads();

    // ---- combine max, exp, sum, write P tile ----
#pragma unroll
    for (int e = 0; e < 4; e++) {
        const int r = lg * 4 + e;
        const float m = fmaxf(fmaxf(red[0][0][r], red[0][1][r]),
                              fmaxf(red[0][2][r], red[0][3][r]));
        float s = 0.f;
#pragma unroll
        for (int nt = 0; nt < 8; nt++) {
            float p = __expf(acc[nt][e] - m);
            acc[nt][e] = p;
            s += p;
        }
        s += __shfl_xor(s, 1); s += __shfl_xor(s, 2);
        s += __shfl_xor(s, 4); s += __shfl_xor(s, 8);
        red[1][w][r] = s;
#pragma unroll
        for (int nt = 0; nt < 8; nt++) {
            const int kcol = w * 128 + nt * 16 + lr;
            int byte = r * 1024 + kcol * 2;
            byte ^= (r & 7) << 4;
            *(short*)((char*)PS + byte) = f2bits(acc[nt][e]);
        }
    }
    __syncthreads();

    // ---- PV: wave w owns d in [w*16, w*16+16), k-loop over all 512 ----
    floatx4 accO = (floatx4){0.f, 0.f, 0.f, 0.f};
#pragma unroll
    for (int ks = 0; ks < 16; ks++) {
        const int qr = lr;                       // A-frag row = q
        int byte = qr * 1024 + (ks * 32 + lg * 8) * 2;
        byte ^= (qr & 7) << 4;
        short8 pa = *(const short8*)((char*)PS + byte);
        short8 vb = *(const short8*)(Vtb + (long)(w * 16 + lr) * SEQ + ks * 32 + lg * 8);
        accO = __builtin_amdgcn_mfma_f32_16x16x32_bf16(pa, vb, accO, 0, 0, 0);
    }

    // ---- normalize + write ----
    const int b = bh >> 4, h = bh & 15;
#pragma unroll
    for (int e = 0; e < 4; e++) {
        const int r = lg * 4 + e;
        const float rs = red[1][0][r] + red[1][1][r] + red[1][2][r] + red[1][3][r];
        const float v = accO[e] / rs;
        attnO[((long)(b * SEQ + q0 + r)) * HIDDEN + h * HEAD_DIM + w * 16 + lr] = f2bits(v);
    }
}

// ---------------------------------------------------------------------------
extern "C" void kernel_launch(void* const* d_in, const int* in_sizes, int n_in,
                              void* d_out, int out_size, void* d_ws, size_t ws_size,
                              hipStream_t stream)
{
    const float* inputs = (const float*)d_in[0];
    const float* rel    = (const float*)d_in[1];
    const float* Wq     = (const float*)d_in[2];
    const float* bq     = (const float*)d_in[3];
    const float* Wk     = (const float*)d_in[4];
    const float* bk     = (const float*)d_in[5];
    const float* Wv     = (const float*)d_in[6];
    const float* bv     = (const float*)d_in[7];
    const float* Wo     = (const float*)d_in[8];
    const float* bo     = (const float*)d_in[9];
    float* out = (float*)d_out;

    char* ws = (char*)d_ws;
    size_t off = 0;
    auto alloc = [&](size_t bytes) -> char* {
        char* p = ws + off;
        off += (bytes + 255) & ~(size_t)255;
        return p;
    };
    short* inA   = (short*)alloc(4194304ull * 2);
    short* inRel = (short*)alloc(4194304ull * 2);
    short* WqT   = (short*)alloc(1048576ull * 2);   // WqT/WkT/WvT contiguous ->
    short* WkT   = (short*)alloc(1048576ull * 2);   // concat B for fused GEMMs
    short* WvT   = (short*)alloc(1048576ull * 2);
    short* WoT   = (short*)alloc(1048576ull * 2);
    short* Qw    = (short*)alloc(4194304ull * 2);
    short* Kw    = (short*)alloc(4194304ull * 2);
    short* Vtw   = (short*)alloc(4194304ull * 2);
    short* posQw = (short*)alloc(4194304ull * 2);
    short* posKw = (short*)alloc(4194304ull * 2);
    short* c2pW  = (short*)alloc(33554432ull * 2);
    short* p2cW  = (short*)alloc(33554432ull * 2);
    short* attnW = (short*)alloc(4194304ull * 2);
    int*   ftabW = (int*)alloc(4096);

    // prep
    conv_pair<<<4096, 256, 0, stream>>>(inputs, rel, inA, inRel);
    wtrans<<<dim3(16, 16, 4), 256, 0, stream>>>(Wq, Wk, Wv, Wo, WqT, WkT, WvT, WoT);
    ftab_build<<<4, 256, 0, stream>>>(ftabW);

    // fused QKV projection (N=3072) and posQ/posK projection (N=2048)
    gemm_nt<4><<<dim3(32, 24), 256, 0, stream>>>(inA, 0, 1024, WqT, 0, 1024,
                                                 Qw, Kw, Vtw, 0, 0, bq, bk, bv, 1024);
    gemm_nt<5><<<dim3(32, 16), 256, 0, stream>>>(inRel, 0, 1024, WqT, 0, 1024,
                                                 posQw, posKw, nullptr, 0, 0, bq, bk, nullptr, 1024);

    // c2pfull = Q @ posK^T  [q,p];  p2cT = posQ @ K^T  [p,k]  (batched over bh)
    dim3 gs(4, 4, 128);
    gemm_nt<1><<<gs, 256, 0, stream>>>(Qw,    32768, 64, posKw, 32768, 64,
                                       c2pW, nullptr, nullptr, 262144, 512, nullptr, nullptr, nullptr, 64);
    gemm_nt<1><<<gs, 256, 0, stream>>>(posQw, 32768, 64, Kw,    32768, 64,
                                       p2cW, nullptr, nullptr, 262144, 512, nullptr, nullptr, nullptr, 64);

    // fused scores+gather+softmax+PV
    attn_fused<<<4096, 256, 0, stream>>>(Qw, Kw, Vtw, c2pW, p2cW, ftabW, attnW);

    // output projection (fp32 out + bias)
    gemm_nt<2><<<dim3(32, 8), 256, 0, stream>>>(attnW, 0, 1024, WoT, 0, 1024,
                                                out, nullptr, nullptr, 0, 1024, bo, nullptr, nullptr, 1024);
}